// Round 11
// baseline (188.061 us; speedup 1.0000x reference)
//
#include <hip/hip_runtime.h>
#include <hip/hip_bf16.h>

// GPT2 attention: hidden[2,2048,1024] -> qkv gemm -> causal MFMA flash attn
// (single-tile split-K chunks + merge) -> proj
// ws layout (48 MB):
//   hA     bf16 8 MB @ 0      (gemm_qkv A input; dead after -> attn partial
//                              overflow region P1, 4 MB used)
//   wqkvT  bf16 6 MB @ 8 MB   (dead after gemm_qkv -> lp partials, 655 KB)
//   wprojT bf16 2 MB @ 14 MB
//   qkv    bf16 24 MB @ 16 MB (Q scaled by log2(e)/8)
//   vA     bf16 8 MB @ 40 MB  (V in PV-frag layout from gemm epilogue; dead
//                              after attn -> merge writes aout here)
// d_out (16 MB): attn partial region P0 (slots 0..2047), later proj output.
//
// qkv GEMM: 8-phase 256x256 schedule (m201 template), BK=64, 8 waves.
// proj GEMM: 8-phase 128x128, 4 waves, grid 8x32 = 256 blocks = 1/CU.
// Attention v9: 1 WAVE x 64 Q-ROWS, barrier-free. Chain-fattening (R9's only
// positive lever, +10%) taken to the limit: 96 MFMA + 256 exp per tile-chain,
// ~16 chains/SIMD. With ONE wave per block, direct per-wave K loads cost
// exactly 8 requests/block-tile -- identical to the LDS-staged path (R7's 4x
// blowup was 4 waves x 8) -- so LDS and __syncthreads are dropped outright.
// K issued before V each tile; per-jm transient S keeps VGPR ~230.

typedef __attribute__((ext_vector_type(4))) float  float4v;
typedef __attribute__((ext_vector_type(8))) short  short8v;
typedef __attribute__((ext_vector_type(4))) short  short4v;

#define ATT_SCALE 0.18033688011112042f   // log2(e) / sqrt(64)

__device__ __forceinline__ short f2bf(float f) {
  union { float f; unsigned u; } v; v.f = f;
  unsigned r = v.u + 0x7fffu + ((v.u >> 16) & 1u);   // RNE
  return (short)(r >> 16);
}
__device__ __forceinline__ float bf2f(short s) {
  union { unsigned u; float f; } v; v.u = ((unsigned)(unsigned short)s) << 16;
  return v.f;
}

// pack 4 floats -> 4 bf16 (round-half-up) via v_perm_b32
__device__ __forceinline__ short4v pack_bf16x4(float a, float b, float c, float d) {
  unsigned x0 = __builtin_bit_cast(unsigned, a) + 0x8000u;
  unsigned x1 = __builtin_bit_cast(unsigned, b) + 0x8000u;
  unsigned x2 = __builtin_bit_cast(unsigned, c) + 0x8000u;
  unsigned x3 = __builtin_bit_cast(unsigned, d) + 0x8000u;
  union { unsigned u[2]; short4v s; } r;
  r.u[0] = __builtin_amdgcn_perm(x1, x0, 0x07060302);
  r.u[1] = __builtin_amdgcn_perm(x3, x2, 0x07060302);
  return r.s;
}

// pack 4 floats -> 4 bf16 (RNE) via v_cvt_pk_bf16_f32
__device__ __forceinline__ short4v cvt_pk_bf16x4(float a, float b, float c, float d) {
  union { unsigned u[2]; short4v s; } r;
  asm("v_cvt_pk_bf16_f32 %0, %1, %2" : "=v"(r.u[0]) : "v"(a), "v"(b));
  asm("v_cvt_pk_bf16_f32 %0, %1, %2" : "=v"(r.u[1]) : "v"(c), "v"(d));
  return r.s;
}

// async global->LDS, 16B per lane; LDS dest = wave-uniform base + lane*16
__device__ __forceinline__ void gl_lds16(const void* g, void* l) {
  __builtin_amdgcn_global_load_lds(
      (const __attribute__((address_space(1))) unsigned*)g,
      (__attribute__((address_space(3))) unsigned*)l, 16, 0, 0);
}

// ---------------- merged prep: hidden->bf16, both weight transposes ----------
__global__ __launch_bounds__(256) void prep_kernel(
    const float* __restrict__ hidden, const float* __restrict__ w_attn,
    const float* __restrict__ w_proj, short* __restrict__ hA,
    short* __restrict__ wqkvT, short* __restrict__ wprojT) {
  __shared__ float tile[32][33];
  const int bx = blockIdx.x, t = threadIdx.x;
  if (bx < 4096) {                     // hidden [4096,1024] fp32 -> bf16
    const size_t i = ((size_t)bx * 256 + t) * 4;
    float4v v = *(const float4v*)(hidden + i);
    short4v o;
    #pragma unroll
    for (int k = 0; k < 4; k++) o[k] = f2bf(v[k]);
    *(short4v*)(hA + i) = o;
    return;
  }
  const float* in; short* out; int R, C, cx, cy;
  if (bx < 4096 + 3072) {              // w_attn [1024,3072] -> [3072,1024]
    in = w_attn; out = wqkvT; R = 1024; C = 3072;
    cx = (bx - 4096) % 96; cy = (bx - 4096) / 96;
  } else {                             // w_proj [1024,1024] -> [1024,1024]
    in = w_proj; out = wprojT; R = 1024; C = 1024;
    cx = (bx - 7168) % 32; cy = (bx - 7168) / 32;
  }
  const int tx = t & 31, ty = t >> 5;  // 32 x 8
  const int c0 = cx * 32, r0 = cy * 32;
  #pragma unroll
  for (int i = 0; i < 4; i++)
    tile[ty + i * 8][tx] = in[(size_t)(r0 + ty + i * 8) * C + c0 + tx];
  __syncthreads();
  #pragma unroll
  for (int i = 0; i < 4; i++) {
    const int cc = ty + i * 8;
    out[(size_t)(c0 + cc) * R + r0 + tx] = f2bf(tile[tx][cc]);
  }
}

// ---------------- qkv GEMM: 8-phase 256x256, BK=64, 8 waves ----------------
__global__ __launch_bounds__(512, 2) void gemm_qkv256(
    const short* __restrict__ A, const short* __restrict__ Bt,
    const float* __restrict__ bias, short* __restrict__ qkv,
    short* __restrict__ vA)
{
  __shared__ short As[2][256][64];   // 64 KB
  __shared__ short Bs[2][256][64];   // 64 KB
  const int K = 1024;
  const int t = threadIdx.x;
  const int lane = t & 63, w = t >> 6;          // 8 waves
  const int wm2 = w >> 2, wn4 = w & 3;          // 2M x 4N wave grid
  const int l16 = lane & 15, quad = lane >> 4;
  const int e7 = l16 & 7;                       // read-side swizzle key
  const int row0 = blockIdx.y * 256;
  const int col0 = blockIdx.x * 256;

  float4v acc[8][4] = {};

  const int srow = w * 8 + (lane >> 3);
  const int slog = (lane & 7) ^ (lane >> 3);
  const short* gA = A + (size_t)(row0 + srow) * K + slog * 8;
  const short* gB = Bt + (size_t)(col0 + srow) * K + slog * 8;
  const int sdst = (lane & 7) * 8;              // within-row shorts

  auto stageA = [&](int b, int qd, int kt) {
    gl_lds16(gA + (size_t)qd * 64 * K + kt * 64,
             &As[b][qd * 64 + w * 8 + (lane >> 3)][sdst]);
  };
  auto stageB = [&](int b, int qd, int kt) {
    gl_lds16(gB + (size_t)qd * 64 * K + kt * 64,
             &Bs[b][qd * 64 + w * 8 + (lane >> 3)][sdst]);
  };

  short8v af[4], bf0[4], bf1[4];
  auto ldA = [&](int b, int mh, int ks) {
    #pragma unroll
    for (int m = 0; m < 4; m++) {
      const int row = wm2 * 128 + mh * 64 + m * 16 + l16;
      af[m] = *(const short8v*)&As[b][row][((ks * 4 + quad) ^ e7) * 8];
    }
  };
  auto ldB = [&](short8v* bf, int b, int ks) {
    #pragma unroll
    for (int n = 0; n < 4; n++) {
      const int row = wn4 * 64 + n * 16 + l16;
      bf[n] = *(const short8v*)&Bs[b][row][((ks * 4 + quad) ^ e7) * 8];
    }
  };
  auto mm = [&](int mb, short8v* bf) {
    __builtin_amdgcn_s_setprio(1);
    #pragma unroll
    for (int m = 0; m < 4; m++)
      #pragma unroll
      for (int n = 0; n < 4; n++)
        acc[mb + m][n] =
            __builtin_amdgcn_mfma_f32_16x16x32_bf16(af[m], bf[n], acc[mb + m][n], 0, 0, 0);
    __builtin_amdgcn_s_setprio(0);
  };
  auto sync_mfma = [&]() {           // barrier -> lgkm drain (rule #18 fence)
    __builtin_amdgcn_sched_barrier(0);
    __builtin_amdgcn_s_barrier();
    asm volatile("s_waitcnt lgkmcnt(0)" ::: "memory");
    __builtin_amdgcn_sched_barrier(0);
  };
  auto endp = [&]() {                // trailing phase barrier
    __builtin_amdgcn_sched_barrier(0);
    __builtin_amdgcn_s_barrier();
    __builtin_amdgcn_sched_barrier(0);
  };

  // prologue: tile 0 (A+B, 8 quarters) + tile 1 B (4 quarters)
  #pragma unroll
  for (int qd = 0; qd < 4; qd++) stageA(0, qd, 0);
  #pragma unroll
  for (int qd = 0; qd < 4; qd++) stageB(0, qd, 0);
  #pragma unroll
  for (int qd = 0; qd < 4; qd++) stageB(1, qd, 1);
  asm volatile("s_waitcnt vmcnt(4)" ::: "memory");   // tile 0 landed
  __builtin_amdgcn_s_barrier();
  __builtin_amdgcn_sched_barrier(0);

  const int NIT = K / 128;           // 8 iterations, 2 K-tiles each
  #pragma unroll 1
  for (int it = 0; it < NIT; it++) {
    const bool st = (it < NIT - 1);  // last iter: no new stages
    const int t1 = 2 * it + 1, t2 = 2 * it + 2, t3 = 2 * it + 3;

    // ---- K-tile even (buf0) ----
    ldA(0, 0, 0); ldB(bf0, 0, 0);
    stageA(1, 0, t1); stageA(1, 1, t1);
    sync_mfma(); mm(0, bf0); endp();
    ldA(0, 0, 1); ldB(bf1, 0, 1);
    stageA(1, 2, t1); stageA(1, 3, t1);
    sync_mfma(); mm(0, bf1); endp();
    ldA(0, 1, 0);
    if (st) { stageB(0, 0, t2); stageB(0, 1, t2); }
    sync_mfma(); mm(4, bf0); endp();
    ldA(0, 1, 1);
    if (st) { stageB(0, 2, t2); stageB(0, 3, t2); }
    if (st) asm volatile("s_waitcnt vmcnt(4)" ::: "memory");
    else    asm volatile("s_waitcnt vmcnt(0)" ::: "memory");
    sync_mfma(); mm(4, bf1); endp();

    // ---- K-tile odd (buf1) ----
    ldA(1, 0, 0); ldB(bf0, 1, 0);
    if (st) { stageA(0, 0, t2); stageA(0, 1, t2); }
    sync_mfma(); mm(0, bf0); endp();
    ldA(1, 0, 1); ldB(bf1, 1, 1);
    if (st) { stageA(0, 2, t2); stageA(0, 3, t2); }
    sync_mfma(); mm(0, bf1); endp();
    ldA(1, 1, 0);
    if (st) { stageB(1, 0, t3); stageB(1, 1, t3); }
    sync_mfma(); mm(4, bf0); endp();
    ldA(1, 1, 1);
    if (st) { stageB(1, 2, t3); stageB(1, 3, t3); }
    if (st) asm volatile("s_waitcnt vmcnt(4)" ::: "memory");
    sync_mfma(); mm(4, bf1); endp();
  }

  // ---------------- epilogue ----------------
  if (col0 >= 2048) {                // V: PV-fragment-major scatter into vA
    const int b  = row0 >> 11;
    const int hh = ((col0 - 2048) >> 6) + wn4;
    #pragma unroll
    for (int ktl = 0; ktl < 2; ktl++) {
      const int kt = ((row0 & 2047) >> 6) + wm2 * 2 + ktl;
      short* vbase = vA + ((size_t)((b * 16 + hh) * 32 + kt) * 8) * 512;
      #pragma unroll
      for (int j = 0; j < 4; j++) {
        const float bv = bias[col0 + wn4 * 64 + j * 16 + l16];
        #pragma unroll
        for (int kwp = 0; kwp < 2; kwp++) {
          short8v s8;
          #pragma unroll
          for (int kw = 0; kw < 2; kw++) {
            const int mi = ktl * 4 + kwp * 2 + kw;
            short4v q4 = pack_bf16x4(acc[mi][j][0] + bv, acc[mi][j][1] + bv,
                                     acc[mi][j][2] + bv, acc[mi][j][3] + bv);
            #pragma unroll
            for (int r = 0; r < 4; r++) s8[kw * 4 + r] = q4[r];
          }
          *(short8v*)(vbase + ((size_t)(kwp * 4 + j) * 64 + lane) * 8) = s8;
        }
      }
    }
    return;
  }
  #pragma unroll
  for (int j = 0; j < 4; j++) {      // Q (scaled) / K
    const int col = col0 + wn4 * 64 + j * 16 + l16;
    const float sc = (col < 1024) ? ATT_SCALE : 1.0f;
    const float bv = bias[col];
    #pragma unroll
    for (int mi = 0; mi < 8; mi++) {
      #pragma unroll
      for (int r = 0; r < 4; r++) {
        const int row = row0 + wm2 * 128 + mi * 16 + quad * 4 + r;
        qkv[(size_t)row * 3072 + col] = f2bf((acc[mi][j][r] + bv) * sc);
      }
    }
  }
}

// ---------------- proj GEMM: 8-phase 128x128, BK=64, 4 waves ---------------
__global__ __launch_bounds__(256, 2) void gemm_proj128(
    const short* __restrict__ A, const short* __restrict__ Bt,
    const float* __restrict__ bias, float* __restrict__ Cout)
{
  __shared__ short As[2][128][64];   // 32 KB
  __shared__ short Bs[2][128][64];   // 32 KB
  const int K = 1024;
  const int t = threadIdx.x;
  const int lane = t & 63, w = t >> 6;          // 4 waves
  const int wm2 = w >> 1, wn2 = w & 1;          // 2M x 2N wave grid
  const int l16 = lane & 15, quad = lane >> 4;
  const int e7 = l16 & 7;                       // read-side swizzle key
  const int row0 = blockIdx.y * 128;
  const int col0 = blockIdx.x * 128;

  float4v acc[4][4] = {};

  const int srow = w * 8 + (lane >> 3);         // 0..31
  const int slog = (lane & 7) ^ (lane >> 3);
  const short* gA = A + (size_t)(row0 + srow) * K + slog * 8;
  const short* gB = Bt + (size_t)(col0 + srow) * K + slog * 8;
  const int sdst = (lane & 7) * 8;

  auto stageA = [&](int b, int qd, int kt) {
    gl_lds16(gA + (size_t)qd * 32 * K + kt * 64,
             &As[b][qd * 32 + w * 8 + (lane >> 3)][sdst]);
  };
  auto stageB = [&](int b, int qd, int kt) {
    gl_lds16(gB + (size_t)qd * 32 * K + kt * 64,
             &Bs[b][qd * 32 + w * 8 + (lane >> 3)][sdst]);
  };

  short8v af[2], bf0[4], bf1[4];
  auto ldA = [&](int b, int mh, int ks) {
    #pragma unroll
    for (int m = 0; m < 2; m++) {
      const int row = wm2 * 64 + mh * 32 + m * 16 + l16;
      af[m] = *(const short8v*)&As[b][row][((ks * 4 + quad) ^ e7) * 8];
    }
  };
  auto ldB = [&](short8v* bf, int b, int ks) {
    #pragma unroll
    for (int n = 0; n < 4; n++) {
      const int row = wn2 * 64 + n * 16 + l16;
      bf[n] = *(const short8v*)&Bs[b][row][((ks * 4 + quad) ^ e7) * 8];
    }
  };
  auto mm = [&](int mb, short8v* bf) {
    __builtin_amdgcn_s_setprio(1);
    #pragma unroll
    for (int m = 0; m < 2; m++)
      #pragma unroll
      for (int n = 0; n < 4; n++)
        acc[mb + m][n] =
            __builtin_amdgcn_mfma_f32_16x16x32_bf16(af[m], bf[n], acc[mb + m][n], 0, 0, 0);
    __builtin_amdgcn_s_setprio(0);
  };
  auto sync_mfma = [&]() {
    __builtin_amdgcn_sched_barrier(0);
    __builtin_amdgcn_s_barrier();
    asm volatile("s_waitcnt lgkmcnt(0)" ::: "memory");
    __builtin_amdgcn_sched_barrier(0);
  };
  auto endp = [&]() {
    __builtin_amdgcn_sched_barrier(0);
    __builtin_amdgcn_s_barrier();
    __builtin_amdgcn_sched_barrier(0);
  };

  // prologue: tile 0 (A+B, 8 quarters) + tile 1 B (4 quarters)
  #pragma unroll
  for (int qd = 0; qd < 4; qd++) stageA(0, qd, 0);
  #pragma unroll
  for (int qd = 0; qd < 4; qd++) stageB(0, qd, 0);
  #pragma unroll
  for (int qd = 0; qd < 4; qd++) stageB(1, qd, 1);
  asm volatile("s_waitcnt vmcnt(4)" ::: "memory");   // tile 0 landed
  __builtin_amdgcn_s_barrier();
  __builtin_amdgcn_sched_barrier(0);

  const int NIT = K / 128;           // 8 iterations, 2 K-tiles each
  #pragma unroll 1
  for (int it = 0; it < NIT; it++) {
    const bool st = (it < NIT - 1);
    const int t1 = 2 * it + 1, t2 = 2 * it + 2, t3 = 2 * it + 3;

    // ---- K-tile even (buf0) ----
    ldA(0, 0, 0); ldB(bf0, 0, 0);
    stageA(1, 0, t1); stageA(1, 1, t1);
    sync_mfma(); mm(0, bf0); endp();
    ldA(0, 0, 1); ldB(bf1, 0, 1);
    stageA(1, 2, t1); stageA(1, 3, t1);
    sync_mfma(); mm(0, bf1); endp();
    ldA(0, 1, 0);
    if (st) { stageB(0, 0, t2); stageB(0, 1, t2); }
    sync_mfma(); mm(2, bf0); endp();
    ldA(0, 1, 1);
    if (st) { stageB(0, 2, t2); stageB(0, 3, t2); }
    if (st) asm volatile("s_waitcnt vmcnt(4)" ::: "memory");
    else    asm volatile("s_waitcnt vmcnt(0)" ::: "memory");
    sync_mfma(); mm(2, bf1); endp();

    // ---- K-tile odd (buf1) ----
    ldA(1, 0, 0); ldB(bf0, 1, 0);
    if (st) { stageA(0, 0, t2); stageA(0, 1, t2); }
    sync_mfma(); mm(0, bf0); endp();
    ldA(1, 0, 1); ldB(bf1, 1, 1);
    if (st) { stageA(0, 2, t2); stageA(0, 3, t2); }
    sync_mfma(); mm(0, bf1); endp();
    ldA(1, 1, 0);
    if (st) { stageB(1, 0, t3); stageB(1, 1, t3); }
    sync_mfma(); mm(2, bf0); endp();
    ldA(1, 1, 1);
    if (st) { stageB(1, 2, t3); stageB(1, 3, t3); }
    if (st) asm volatile("s_waitcnt vmcnt(4)" ::: "memory");
    sync_mfma(); mm(2, bf1); endp();
  }

  // epilogue: fp32 out + bias
  #pragma unroll
  for (int j = 0; j < 4; j++) {
    const int col = col0 + wn2 * 64 + j * 16 + l16;
    const float bv = bias[col];
    #pragma unroll
    for (int mi = 0; mi < 4; mi++) {
      #pragma unroll
      for (int r = 0; r < 4; r++) {
        const int row = row0 + wm2 * 64 + mi * 16 + quad * 4 + r;
        Cout[(size_t)row * 1024 + col] = acc[mi][j][r] + bv;
      }
    }
  }
}

// ---------------- MFMA causal flash attention, 1 wave x 64 rows ------------
// Grid (bh = x, slot = y heavy-first), 64 threads = 1 wave per block.
// The wave owns all 64 q-rows of its tile as four 16-row halves. No LDS, no
// barrier: K frags loaded direct (8 requests/block-tile, same count as the
// old staged path), V frags direct, both shared across the 4 halves in
// registers. Per-jm transient S keeps peak VGPR ~230.
__global__ __launch_bounds__(64, 2) void attn_mfma(
    const short* __restrict__ qkv, const short* __restrict__ vA,
    short* __restrict__ P0, short* __restrict__ P1, float* __restrict__ lp)
{
  const int bh = blockIdx.x;
  const int b = bh >> 4, h = bh & 15;
  const int s = 79 - blockIdx.y;     // global heavy-first (LPT) order
  int qt = 0, sbase = 0;             // decode slot -> (qt, c); scalar loop
  for (;;) { const int nc = (qt >> 3) + 1; if (s < sbase + nc) break; sbase += nc; qt++; }
  const int c = s - sbase;
  const int kt0  = c * 8;
  const int kend = min(qt + 1, kt0 + 8);

  const int lane = threadIdx.x & 63;
  const int l16 = lane & 15, quad = lane >> 4;

  const size_t base = (size_t)b * 2048 * 3072;
  const int qoff = h * 64, koff = 1024 + h * 64;

  // four 16-row halves: q rows qt*64 + hh*16 + l16
  int qg[4];
  short8v qf[4][2];                  // [half][ks]
  #pragma unroll
  for (int hh = 0; hh < 4; hh++) {
    qg[hh] = qt * 64 + hh * 16 + l16;
    #pragma unroll
    for (int ks = 0; ks < 2; ks++)
      qf[hh][ks] = *(const short8v*)(qkv + base + (size_t)qg[hh] * 3072
                                     + qoff + ks * 32 + quad * 8);
  }

  float4v O[4][4] = {};
  float l[4] = {0.0f, 0.0f, 0.0f, 0.0f};

  // K frag id = ks*4+jm at addr kg + (kt*64 + jm*16)*3072 + ks*32
  const short* kg = qkv + base + (size_t)l16 * 3072 + koff + quad * 8;
  const short* vg = vA + (size_t)(bh * 32) * 4096 + lane * 8;

  for (int kt = kt0; kt < kend; kt++) {
    // K first (QK's counted wait leaves V outstanding), then V
    short8v kf[8];
    #pragma unroll
    for (int id = 0; id < 8; id++)
      kf[id] = *(const short8v*)(kg + ((size_t)kt * 64 + (id & 3) * 16) * 3072
                                    + (id >> 2) * 32);
    short8v vv[8];
    #pragma unroll
    for (int id = 0; id < 8; id++)
      vv[id] = *(const short8v*)(vg + (size_t)kt * 4096 + id * 512);

    // QK^T + mask + exp + pack, one jm (16-k slab) at a time: S transient
    short4v pk[4][4];                // [half][jm]
    #pragma unroll
    for (int jm = 0; jm < 4; jm++) {
      float4v sv[4] = {};
      __builtin_amdgcn_s_setprio(1);
      #pragma unroll
      for (int hh = 0; hh < 4; hh++)
        sv[hh] = __builtin_amdgcn_mfma_f32_16x16x32_bf16(kf[jm], qf[hh][0],
                                                         sv[hh], 0, 0, 0);
      #pragma unroll
      for (int hh = 0; hh < 4; hh++)
        sv[hh] = __builtin_amdgcn_mfma_f32_16x16x32_bf16(kf[4 + jm], qf[hh][1],
                                                         sv[hh], 0, 0, 0);
      __builtin_amdgcn_s_setprio(0);

      if (kt == qt) {                // diagonal tile: causal mask
        const int kv = kt * 64 + jm * 16 + quad * 4;
        #pragma unroll
        for (int hh = 0; hh < 4; hh++)
          #pragma unroll
          for (int r = 0; r < 4; r++)
            if (kv + r > qg[hh]) sv[hh][r] = -INFINITY;
      }

      #pragma unroll
      for (int hh = 0; hh < 4; hh++) {
        float p0 = __builtin_amdgcn_exp2f(sv[hh][0]);
        float p1 = __builtin_amdgcn_exp2f(sv[hh][1]);
        float p2 = __builtin_amdgcn_exp2f(sv[hh][2]);
        float p3 = __builtin_amdgcn_exp2f(sv[hh][3]);
        l[hh] += (p0 + p1) + (p2 + p3);
        pk[hh][jm] = cvt_pk_bf16x4(p0, p1, p2, p3);
      }
    }

    // O^T += V^T * P^T, V frag reused across the 4 halves
    __builtin_amdgcn_s_setprio(1);
    #pragma unroll
    for (int id = 0; id < 8; id++) {
      const int kwp = id >> 2, dm = id & 3;
      const short8v v8 = vv[id];
      const short4v v0 = {v8[0], v8[1], v8[2], v8[3]};
      const short4v v1 = {v8[4], v8[5], v8[6], v8[7]};
      #pragma unroll
      for (int hh = 0; hh < 4; hh++) {
        O[hh][dm] = __builtin_amdgcn_mfma_f32_16x16x16bf16_1k(v0, pk[hh][kwp * 2],
                                                              O[hh][dm], 0, 0, 0);
        O[hh][dm] = __builtin_amdgcn_mfma_f32_16x16x16bf16_1k(v1, pk[hh][kwp * 2 + 1],
                                                              O[hh][dm], 0, 0, 0);
      }
    }
    __builtin_amdgcn_s_setprio(0);
  }

  // epilogue: reduce l over the quad group; write UNNORMALIZED bf16 partial
  #pragma unroll
  for (int hh = 0; hh < 4; hh++) {
    l[hh] += __shfl_xor(l[hh], 16);
    l[hh] += __shfl_xor(l[hh], 32);
  }
  const int i = bh * 80 + s;
  short* pp = (i < 2048) ? (P0 + (size_t)i * 4096) : (P1 + (size_t)(i - 2048) * 4096);
  #pragma unroll
  for (int hh = 0; hh < 4; hh++) {
    const int row = hh * 16 + l16;
    if (quad == 0) lp[(size_t)i * 64 + row] = l[hh];
    short* pr = pp + row * 64;
    #pragma unroll
    for (int dm = 0; dm < 4; dm++)
      *(short4v*)(pr + dm * 16 + quad * 4) =
          pack_bf16x4(O[hh][dm][0], O[hh][dm][1], O[hh][dm][2], O[hh][dm][3]);
  }
}

// ---------------- merge split-K partials -> normalized bf16 aout ------------
__global__ __launch_bounds__(256) void merge_attn(
    const short* __restrict__ P0, const short* __restrict__ P1,
    const float* __restrict__ lp, short* __restrict__ aout)
{
  const int idx = blockIdx.x * 256 + threadIdx.x;   // 524288
  const int q = idx >> 7;
  const int rest = idx & 127;
  const int h  = rest >> 3;
  const int dg = (rest & 7) * 8;
  const int b  = q >> 11;
  const int qr = q & 2047;
  const int qt = qr >> 6;
  const int row = qr & 63;
  const int a = qt >> 3, bq = qt & 7;
  const int off = qt + 4 * a * (a - 1) + a * bq;
  const int nc  = a + 1;
  const int bh  = b * 16 + h;

  float acc[8] = {};
  float suml = 0.0f;
  for (int c = 0; c < nc; c++) {
    const int i = bh * 80 + off + c;
    const short* pp = (i < 2048) ? (P0 + (size_t)i * 4096) : (P1 + (size_t)(i - 2048) * 4096);
    const short8v o = *(const short8v*)(pp + row * 64 + dg);
    #pragma unroll
    for (int k = 0; k < 8; k++) acc[k] += bf2f(o[k]);
    suml += lp[(size_t)i * 64 + row];
  }
  const float inv = 1.0f / suml;
  short8v ov;
  #pragma unroll
  for (int k = 0; k < 8; k++) ov[k] = f2bf(acc[k] * inv);
  *(short8v*)(aout + (size_t)q * 1024 + h * 64 + dg) = ov;
}

extern "C" void kernel_launch(void* const* d_in, const int* in_sizes, int n_in,
                              void* d_out, int out_size, void* d_ws, size_t ws_size,
                              hipStream_t stream) {
  const float* hidden = (const float*)d_in[0];
  const float* w_attn = (const float*)d_in[1];
  const float* b_attn = (const float*)d_in[2];
  const float* w_proj = (const float*)d_in[3];
  const float* b_proj = (const float*)d_in[4];
  float* outp = (float*)d_out;

  char* ws = (char*)d_ws;
  short* hA     = (short*)(ws);                       // then attn P1 overflow
  float* lp     = (float*)(ws + 8ull  * 1024 * 1024); // 655 KB (ex-wqkvT space)
  short* wqkvT  = (short*)(ws + 8ull  * 1024 * 1024);
  short* wprojT = (short*)(ws + 14ull * 1024 * 1024);
  short* qkvb   = (short*)(ws + 16ull * 1024 * 1024);
  short* vAbuf  = (short*)(ws + 40ull * 1024 * 1024); // V frags, then aout
  short* aout   = (short*)(ws + 40ull * 1024 * 1024);
  short* P0     = (short*)d_out;                      // 16 MB partial region

  prep_kernel<<<8192, 256, 0, stream>>>(hidden, w_attn, w_proj, hA, wqkvT, wprojT);
  gemm_qkv256<<<dim3(12, 16), 512, 0, stream>>>(hA, wqkvT, b_attn, qkvb, vAbuf);
  attn_mfma<<<dim3(32, 80), 64, 0, stream>>>(qkvb, vAbuf, P0, hA, lp);
  merge_attn<<<2048, 256, 0, stream>>>(P0, hA, lp, aout);
  gemm_proj128<<<dim3(8, 32), 256, 0, stream>>>(aout, wprojT, b_proj, outp);
}

// Round 12
// 184.055 us; speedup vs baseline: 1.0218x; 1.0218x over previous
//
#include <hip/hip_runtime.h>
#include <hip/hip_bf16.h>

// GPT2 attention: hidden[2,2048,1024] -> qkv gemm -> causal MFMA flash attn
// (single-tile split-K chunks + merge) -> proj
// ws layout (48 MB):
//   hA     bf16 8 MB @ 0      (gemm_qkv A input; dead after -> attn partial
//                              overflow region P1, 4 MB used)
//   wqkvT  bf16 6 MB @ 8 MB   (dead after gemm_qkv -> lp partials, 655 KB)
//   wprojT bf16 2 MB @ 14 MB
//   qkv    bf16 24 MB @ 16 MB (Q scaled by log2(e)/8)
//   vA     bf16 8 MB @ 40 MB  (V in PV-frag layout from gemm epilogue; dead
//                              after attn -> merge writes aout here)
// d_out (16 MB): attn partial region P0 (slots 0..2047), later proj output.
//
// qkv GEMM v4: 8-phase 256x256 (m201 template) +
//   - bijective XCD swizzle (192 = 8x24, col-major decode): each XCD owns
//     ~1.5 B-panels (~1 MB, L2-resident) instead of all 8 L2s fetching all
//     panels (R11 counters: FETCH 39 MB vs 14 MB read set).
//   - LDS-bounce Q/K epilogue: acc -> bf16 in LDS (quad-keyed XOR swizzle,
//     conflict-free) -> coalesced short8v stores. Replaces 128 scalar 2B
//     stores/thread that caused ~25 MB of partial-line RMW fetch.
// proj GEMM: 8-phase 128x128, 4 waves, grid 8x32 = 256 blocks = 1/CU.
// Attention v9 (R11): 1 wave x 64 q-rows, barrier-free, direct K+V loads.

typedef __attribute__((ext_vector_type(4))) float  float4v;
typedef __attribute__((ext_vector_type(8))) short  short8v;
typedef __attribute__((ext_vector_type(4))) short  short4v;

#define ATT_SCALE 0.18033688011112042f   // log2(e) / sqrt(64)

__device__ __forceinline__ short f2bf(float f) {
  union { float f; unsigned u; } v; v.f = f;
  unsigned r = v.u + 0x7fffu + ((v.u >> 16) & 1u);   // RNE
  return (short)(r >> 16);
}
__device__ __forceinline__ float bf2f(short s) {
  union { unsigned u; float f; } v; v.u = ((unsigned)(unsigned short)s) << 16;
  return v.f;
}

// pack 4 floats -> 4 bf16 (round-half-up) via v_perm_b32
__device__ __forceinline__ short4v pack_bf16x4(float a, float b, float c, float d) {
  unsigned x0 = __builtin_bit_cast(unsigned, a) + 0x8000u;
  unsigned x1 = __builtin_bit_cast(unsigned, b) + 0x8000u;
  unsigned x2 = __builtin_bit_cast(unsigned, c) + 0x8000u;
  unsigned x3 = __builtin_bit_cast(unsigned, d) + 0x8000u;
  union { unsigned u[2]; short4v s; } r;
  r.u[0] = __builtin_amdgcn_perm(x1, x0, 0x07060302);
  r.u[1] = __builtin_amdgcn_perm(x3, x2, 0x07060302);
  return r.s;
}

// pack 4 floats -> 4 bf16 (RNE) via v_cvt_pk_bf16_f32
__device__ __forceinline__ short4v cvt_pk_bf16x4(float a, float b, float c, float d) {
  union { unsigned u[2]; short4v s; } r;
  asm("v_cvt_pk_bf16_f32 %0, %1, %2" : "=v"(r.u[0]) : "v"(a), "v"(b));
  asm("v_cvt_pk_bf16_f32 %0, %1, %2" : "=v"(r.u[1]) : "v"(c), "v"(d));
  return r.s;
}

// async global->LDS, 16B per lane; LDS dest = wave-uniform base + lane*16
__device__ __forceinline__ void gl_lds16(const void* g, void* l) {
  __builtin_amdgcn_global_load_lds(
      (const __attribute__((address_space(1))) unsigned*)g,
      (__attribute__((address_space(3))) unsigned*)l, 16, 0, 0);
}

// ---------------- merged prep: hidden->bf16, both weight transposes ----------
__global__ __launch_bounds__(256) void prep_kernel(
    const float* __restrict__ hidden, const float* __restrict__ w_attn,
    const float* __restrict__ w_proj, short* __restrict__ hA,
    short* __restrict__ wqkvT, short* __restrict__ wprojT) {
  __shared__ float tile[32][33];
  const int bx = blockIdx.x, t = threadIdx.x;
  if (bx < 4096) {                     // hidden [4096,1024] fp32 -> bf16
    const size_t i = ((size_t)bx * 256 + t) * 4;
    float4v v = *(const float4v*)(hidden + i);
    short4v o;
    #pragma unroll
    for (int k = 0; k < 4; k++) o[k] = f2bf(v[k]);
    *(short4v*)(hA + i) = o;
    return;
  }
  const float* in; short* out; int R, C, cx, cy;
  if (bx < 4096 + 3072) {              // w_attn [1024,3072] -> [3072,1024]
    in = w_attn; out = wqkvT; R = 1024; C = 3072;
    cx = (bx - 4096) % 96; cy = (bx - 4096) / 96;
  } else {                             // w_proj [1024,1024] -> [1024,1024]
    in = w_proj; out = wprojT; R = 1024; C = 1024;
    cx = (bx - 7168) % 32; cy = (bx - 7168) / 32;
  }
  const int tx = t & 31, ty = t >> 5;  // 32 x 8
  const int c0 = cx * 32, r0 = cy * 32;
  #pragma unroll
  for (int i = 0; i < 4; i++)
    tile[ty + i * 8][tx] = in[(size_t)(r0 + ty + i * 8) * C + c0 + tx];
  __syncthreads();
  #pragma unroll
  for (int i = 0; i < 4; i++) {
    const int cc = ty + i * 8;
    out[(size_t)(c0 + cc) * R + r0 + tx] = f2bf(tile[tx][cc]);
  }
}

// ---------------- qkv GEMM: 8-phase 256x256, BK=64, 8 waves ----------------
// Single 128 KB LDS pool: As = LDSH[0..32767], Bs = LDSH[32768..65535]
// during the K-loop; the whole pool is reused as the bf16 output stage for
// the coalesced Q/K epilogue.
__global__ __launch_bounds__(512, 2) void gemm_qkv256(
    const short* __restrict__ A, const short* __restrict__ Bt,
    const float* __restrict__ bias, short* __restrict__ qkv,
    short* __restrict__ vA)
{
  __shared__ short LDSH[65536];      // 128 KB
  const int K = 1024;
  const int t = threadIdx.x;
  const int lane = t & 63, w = t >> 6;          // 8 waves
  const int wm2 = w >> 2, wn4 = w & 3;          // 2M x 4N wave grid
  const int l16 = lane & 15, quad = lane >> 4;
  const int e7 = l16 & 7;                       // read-side swizzle key

  // bijective XCD swizzle: 192 blocks = 8 XCD x 24; col-major decode so each
  // XCD's 24 blocks span ~1.5 B-panels (L2-resident).
  const int bid  = blockIdx.y * 12 + blockIdx.x;   // 0..191 (x fastest)
  const int wgid = (bid & 7) * 24 + (bid >> 3);
  const int row0 = (wgid & 15) * 256;
  const int col0 = (wgid >> 4) * 256;

  float4v acc[8][4] = {};

  const int srow = w * 8 + (lane >> 3);
  const int slog = (lane & 7) ^ (lane >> 3);
  const short* gA = A + (size_t)(row0 + srow) * K + slog * 8;
  const short* gB = Bt + (size_t)(col0 + srow) * K + slog * 8;
  const int sdst = (lane & 7) * 8;              // within-row shorts

  auto stageA = [&](int b, int qd, int kt) {
    gl_lds16(gA + (size_t)qd * 64 * K + kt * 64,
             &LDSH[b * 16384 + (qd * 64 + w * 8 + (lane >> 3)) * 64 + sdst]);
  };
  auto stageB = [&](int b, int qd, int kt) {
    gl_lds16(gB + (size_t)qd * 64 * K + kt * 64,
             &LDSH[32768 + b * 16384 + (qd * 64 + w * 8 + (lane >> 3)) * 64 + sdst]);
  };

  short8v af[4], bf0[4], bf1[4];
  auto ldA = [&](int b, int mh, int ks) {
    #pragma unroll
    for (int m = 0; m < 4; m++) {
      const int row = wm2 * 128 + mh * 64 + m * 16 + l16;
      af[m] = *(const short8v*)&LDSH[b * 16384 + row * 64 + ((ks * 4 + quad) ^ e7) * 8];
    }
  };
  auto ldB = [&](short8v* bf, int b, int ks) {
    #pragma unroll
    for (int n = 0; n < 4; n++) {
      const int row = wn4 * 64 + n * 16 + l16;
      bf[n] = *(const short8v*)&LDSH[32768 + b * 16384 + row * 64 + ((ks * 4 + quad) ^ e7) * 8];
    }
  };
  auto mm = [&](int mb, short8v* bf) {
    __builtin_amdgcn_s_setprio(1);
    #pragma unroll
    for (int m = 0; m < 4; m++)
      #pragma unroll
      for (int n = 0; n < 4; n++)
        acc[mb + m][n] =
            __builtin_amdgcn_mfma_f32_16x16x32_bf16(af[m], bf[n], acc[mb + m][n], 0, 0, 0);
    __builtin_amdgcn_s_setprio(0);
  };
  auto sync_mfma = [&]() {           // barrier -> lgkm drain (rule #18 fence)
    __builtin_amdgcn_sched_barrier(0);
    __builtin_amdgcn_s_barrier();
    asm volatile("s_waitcnt lgkmcnt(0)" ::: "memory");
    __builtin_amdgcn_sched_barrier(0);
  };
  auto endp = [&]() {                // trailing phase barrier
    __builtin_amdgcn_sched_barrier(0);
    __builtin_amdgcn_s_barrier();
    __builtin_amdgcn_sched_barrier(0);
  };

  // prologue: tile 0 (A+B, 8 quarters) + tile 1 B (4 quarters)
  #pragma unroll
  for (int qd = 0; qd < 4; qd++) stageA(0, qd, 0);
  #pragma unroll
  for (int qd = 0; qd < 4; qd++) stageB(0, qd, 0);
  #pragma unroll
  for (int qd = 0; qd < 4; qd++) stageB(1, qd, 1);
  asm volatile("s_waitcnt vmcnt(4)" ::: "memory");   // tile 0 landed
  __builtin_amdgcn_s_barrier();
  __builtin_amdgcn_sched_barrier(0);

  const int NIT = K / 128;           // 8 iterations, 2 K-tiles each
  #pragma unroll 1
  for (int it = 0; it < NIT; it++) {
    const bool st = (it < NIT - 1);  // last iter: no new stages
    const int t1 = 2 * it + 1, t2 = 2 * it + 2, t3 = 2 * it + 3;

    // ---- K-tile even (buf0) ----
    ldA(0, 0, 0); ldB(bf0, 0, 0);
    stageA(1, 0, t1); stageA(1, 1, t1);
    sync_mfma(); mm(0, bf0); endp();
    ldA(0, 0, 1); ldB(bf1, 0, 1);
    stageA(1, 2, t1); stageA(1, 3, t1);
    sync_mfma(); mm(0, bf1); endp();
    ldA(0, 1, 0);
    if (st) { stageB(0, 0, t2); stageB(0, 1, t2); }
    sync_mfma(); mm(4, bf0); endp();
    ldA(0, 1, 1);
    if (st) { stageB(0, 2, t2); stageB(0, 3, t2); }
    if (st) asm volatile("s_waitcnt vmcnt(4)" ::: "memory");
    else    asm volatile("s_waitcnt vmcnt(0)" ::: "memory");
    sync_mfma(); mm(4, bf1); endp();

    // ---- K-tile odd (buf1) ----
    ldA(1, 0, 0); ldB(bf0, 1, 0);
    if (st) { stageA(0, 0, t2); stageA(0, 1, t2); }
    sync_mfma(); mm(0, bf0); endp();
    ldA(1, 0, 1); ldB(bf1, 1, 1);
    if (st) { stageA(0, 2, t2); stageA(0, 3, t2); }
    sync_mfma(); mm(0, bf1); endp();
    ldA(1, 1, 0);
    if (st) { stageB(1, 0, t3); stageB(1, 1, t3); }
    sync_mfma(); mm(4, bf0); endp();
    ldA(1, 1, 1);
    if (st) { stageB(1, 2, t3); stageB(1, 3, t3); }
    if (st) asm volatile("s_waitcnt vmcnt(4)" ::: "memory");
    sync_mfma(); mm(4, bf1); endp();
  }

  // ---------------- epilogue ----------------
  if (col0 >= 2048) {                // V: PV-fragment-major scatter into vA
    const int b  = row0 >> 11;
    const int hh = ((col0 - 2048) >> 6) + wn4;
    #pragma unroll
    for (int ktl = 0; ktl < 2; ktl++) {
      const int kt = ((row0 & 2047) >> 6) + wm2 * 2 + ktl;
      short* vbase = vA + ((size_t)((b * 16 + hh) * 32 + kt) * 8) * 512;
      #pragma unroll
      for (int j = 0; j < 4; j++) {
        const float bv = bias[col0 + wn4 * 64 + j * 16 + l16];
        #pragma unroll
        for (int kwp = 0; kwp < 2; kwp++) {
          short8v s8;
          #pragma unroll
          for (int kw = 0; kw < 2; kw++) {
            const int mi = ktl * 4 + kwp * 2 + kw;
            short4v q4 = pack_bf16x4(acc[mi][j][0] + bv, acc[mi][j][1] + bv,
                                     acc[mi][j][2] + bv, acc[mi][j][3] + bv);
            #pragma unroll
            for (int r = 0; r < 4; r++) s8[kw * 4 + r] = q4[r];
          }
          *(short8v*)(vbase + ((size_t)(kwp * 4 + j) * 64 + lane) * 8) = s8;
        }
      }
    }
    return;
  }

  // Q/K: LDS-bounce epilogue. Stage the whole 256x256 bf16 tile in LDSH
  // (exactly 128 KB) with a quad-keyed XOR swizzle (key = ((row>>2)&3)<<4:
  // the 4 quads of one ds_write land in disjoint bank groups), then 16
  // coalesced passes of ds_read_b128 + short8v global stores (full 64B
  // lines -- kills the partial-line RMW fetch of the old 2B scalar stores).
  __syncthreads();                   // K-loop done; LDS free for reuse
  #pragma unroll
  for (int j = 0; j < 4; j++) {
    const int col = wn4 * 64 + j * 16 + l16;
    const float sc = (col0 + col < 1024) ? ATT_SCALE : 1.0f;
    const float bv = bias[col0 + col];
    #pragma unroll
    for (int mi = 0; mi < 8; mi++) {
      const int rowb = wm2 * 128 + mi * 16 + quad * 4;
      const int key = ((rowb >> 2) & 3) << 4;    // = quad key, row-invariant
      #pragma unroll
      for (int r = 0; r < 4; r++)
        LDSH[(rowb + r) * 256 + (col ^ key)] = f2bf((acc[mi][j][r] + bv) * sc);
    }
  }
  __syncthreads();
  #pragma unroll
  for (int p = 0; p < 16; p++) {
    const int idx = p * 512 + t;     // 0..8191
    const int r   = idx >> 5;        // 0..255
    const int c8  = (idx & 31) << 3; // 0,8,..,248
    const int cp  = c8 ^ (((r >> 2) & 3) << 4);
    const short8v v = *(const short8v*)&LDSH[r * 256 + cp];
    *(short8v*)(qkv + (size_t)(row0 + r) * 3072 + col0 + c8) = v;
  }
}

// ---------------- proj GEMM: 8-phase 128x128, BK=64, 4 waves ---------------
__global__ __launch_bounds__(256, 2) void gemm_proj128(
    const short* __restrict__ A, const short* __restrict__ Bt,
    const float* __restrict__ bias, float* __restrict__ Cout)
{
  __shared__ short As[2][128][64];   // 32 KB
  __shared__ short Bs[2][128][64];   // 32 KB
  const int K = 1024;
  const int t = threadIdx.x;
  const int lane = t & 63, w = t >> 6;          // 4 waves
  const int wm2 = w >> 1, wn2 = w & 1;          // 2M x 2N wave grid
  const int l16 = lane & 15, quad = lane >> 4;
  const int e7 = l16 & 7;                       // read-side swizzle key
  const int row0 = blockIdx.y * 128;
  const int col0 = blockIdx.x * 128;

  float4v acc[4][4] = {};

  const int srow = w * 8 + (lane >> 3);         // 0..31
  const int slog = (lane & 7) ^ (lane >> 3);
  const short* gA = A + (size_t)(row0 + srow) * K + slog * 8;
  const short* gB = Bt + (size_t)(col0 + srow) * K + slog * 8;
  const int sdst = (lane & 7) * 8;

  auto stageA = [&](int b, int qd, int kt) {
    gl_lds16(gA + (size_t)qd * 32 * K + kt * 64,
             &As[b][qd * 32 + w * 8 + (lane >> 3)][sdst]);
  };
  auto stageB = [&](int b, int qd, int kt) {
    gl_lds16(gB + (size_t)qd * 32 * K + kt * 64,
             &Bs[b][qd * 32 + w * 8 + (lane >> 3)][sdst]);
  };

  short8v af[2], bf0[4], bf1[4];
  auto ldA = [&](int b, int mh, int ks) {
    #pragma unroll
    for (int m = 0; m < 2; m++) {
      const int row = wm2 * 64 + mh * 32 + m * 16 + l16;
      af[m] = *(const short8v*)&As[b][row][((ks * 4 + quad) ^ e7) * 8];
    }
  };
  auto ldB = [&](short8v* bf, int b, int ks) {
    #pragma unroll
    for (int n = 0; n < 4; n++) {
      const int row = wn2 * 64 + n * 16 + l16;
      bf[n] = *(const short8v*)&Bs[b][row][((ks * 4 + quad) ^ e7) * 8];
    }
  };
  auto mm = [&](int mb, short8v* bf) {
    __builtin_amdgcn_s_setprio(1);
    #pragma unroll
    for (int m = 0; m < 2; m++)
      #pragma unroll
      for (int n = 0; n < 4; n++)
        acc[mb + m][n] =
            __builtin_amdgcn_mfma_f32_16x16x32_bf16(af[m], bf[n], acc[mb + m][n], 0, 0, 0);
    __builtin_amdgcn_s_setprio(0);
  };
  auto sync_mfma = [&]() {
    __builtin_amdgcn_sched_barrier(0);
    __builtin_amdgcn_s_barrier();
    asm volatile("s_waitcnt lgkmcnt(0)" ::: "memory");
    __builtin_amdgcn_sched_barrier(0);
  };
  auto endp = [&]() {
    __builtin_amdgcn_sched_barrier(0);
    __builtin_amdgcn_s_barrier();
    __builtin_amdgcn_sched_barrier(0);
  };

  // prologue: tile 0 (A+B, 8 quarters) + tile 1 B (4 quarters)
  #pragma unroll
  for (int qd = 0; qd < 4; qd++) stageA(0, qd, 0);
  #pragma unroll
  for (int qd = 0; qd < 4; qd++) stageB(0, qd, 0);
  #pragma unroll
  for (int qd = 0; qd < 4; qd++) stageB(1, qd, 1);
  asm volatile("s_waitcnt vmcnt(4)" ::: "memory");   // tile 0 landed
  __builtin_amdgcn_s_barrier();
  __builtin_amdgcn_sched_barrier(0);

  const int NIT = K / 128;           // 8 iterations, 2 K-tiles each
  #pragma unroll 1
  for (int it = 0; it < NIT; it++) {
    const bool st = (it < NIT - 1);
    const int t1 = 2 * it + 1, t2 = 2 * it + 2, t3 = 2 * it + 3;

    // ---- K-tile even (buf0) ----
    ldA(0, 0, 0); ldB(bf0, 0, 0);
    stageA(1, 0, t1); stageA(1, 1, t1);
    sync_mfma(); mm(0, bf0); endp();
    ldA(0, 0, 1); ldB(bf1, 0, 1);
    stageA(1, 2, t1); stageA(1, 3, t1);
    sync_mfma(); mm(0, bf1); endp();
    ldA(0, 1, 0);
    if (st) { stageB(0, 0, t2); stageB(0, 1, t2); }
    sync_mfma(); mm(2, bf0); endp();
    ldA(0, 1, 1);
    if (st) { stageB(0, 2, t2); stageB(0, 3, t2); }
    if (st) asm volatile("s_waitcnt vmcnt(4)" ::: "memory");
    else    asm volatile("s_waitcnt vmcnt(0)" ::: "memory");
    sync_mfma(); mm(2, bf1); endp();

    // ---- K-tile odd (buf1) ----
    ldA(1, 0, 0); ldB(bf0, 1, 0);
    if (st) { stageA(0, 0, t2); stageA(0, 1, t2); }
    sync_mfma(); mm(0, bf0); endp();
    ldA(1, 0, 1); ldB(bf1, 1, 1);
    if (st) { stageA(0, 2, t2); stageA(0, 3, t2); }
    sync_mfma(); mm(0, bf1); endp();
    ldA(1, 1, 0);
    if (st) { stageB(1, 0, t3); stageB(1, 1, t3); }
    sync_mfma(); mm(2, bf0); endp();
    ldA(1, 1, 1);
    if (st) { stageB(1, 2, t3); stageB(1, 3, t3); }
    if (st) asm volatile("s_waitcnt vmcnt(4)" ::: "memory");
    sync_mfma(); mm(2, bf1); endp();
  }

  // epilogue: fp32 out + bias
  #pragma unroll
  for (int j = 0; j < 4; j++) {
    const int col = col0 + wn2 * 64 + j * 16 + l16;
    const float bv = bias[col];
    #pragma unroll
    for (int mi = 0; mi < 4; mi++) {
      #pragma unroll
      for (int r = 0; r < 4; r++) {
        const int row = row0 + wm2 * 64 + mi * 16 + quad * 4 + r;
        Cout[(size_t)row * 1024 + col] = acc[mi][j][r] + bv;
      }
    }
  }
}

// ---------------- MFMA causal flash attention, 1 wave x 64 rows ------------
// Grid (bh = x, slot = y heavy-first), 64 threads = 1 wave per block.
// No LDS, no barrier: K frags loaded direct (8 requests/block-tile), V frags
// direct, both shared across the 4 row-halves in registers.
__global__ __launch_bounds__(64, 2) void attn_mfma(
    const short* __restrict__ qkv, const short* __restrict__ vA,
    short* __restrict__ P0, short* __restrict__ P1, float* __restrict__ lp)
{
  const int bh = blockIdx.x;
  const int b = bh >> 4, h = bh & 15;
  const int s = 79 - blockIdx.y;     // global heavy-first (LPT) order
  int qt = 0, sbase = 0;             // decode slot -> (qt, c); scalar loop
  for (;;) { const int nc = (qt >> 3) + 1; if (s < sbase + nc) break; sbase += nc; qt++; }
  const int c = s - sbase;
  const int kt0  = c * 8;
  const int kend = min(qt + 1, kt0 + 8);

  const int lane = threadIdx.x & 63;
  const int l16 = lane & 15, quad = lane >> 4;

  const size_t base = (size_t)b * 2048 * 3072;
  const int qoff = h * 64, koff = 1024 + h * 64;

  // four 16-row halves: q rows qt*64 + hh*16 + l16
  int qg[4];
  short8v qf[4][2];                  // [half][ks]
  #pragma unroll
  for (int hh = 0; hh < 4; hh++) {
    qg[hh] = qt * 64 + hh * 16 + l16;
    #pragma unroll
    for (int ks = 0; ks < 2; ks++)
      qf[hh][ks] = *(const short8v*)(qkv + base + (size_t)qg[hh] * 3072
                                     + qoff + ks * 32 + quad * 8);
  }

  float4v O[4][4] = {};
  float l[4] = {0.0f, 0.0f, 0.0f, 0.0f};

  // K frag id = ks*4+jm at addr kg + (kt*64 + jm*16)*3072 + ks*32
  const short* kg = qkv + base + (size_t)l16 * 3072 + koff + quad * 8;
  const short* vg = vA + (size_t)(bh * 32) * 4096 + lane * 8;

  for (int kt = kt0; kt < kend; kt++) {
    // K first (QK's counted wait leaves V outstanding), then V
    short8v kf[8];
    #pragma unroll
    for (int id = 0; id < 8; id++)
      kf[id] = *(const short8v*)(kg + ((size_t)kt * 64 + (id & 3) * 16) * 3072
                                    + (id >> 2) * 32);
    short8v vv[8];
    #pragma unroll
    for (int id = 0; id < 8; id++)
      vv[id] = *(const short8v*)(vg + (size_t)kt * 4096 + id * 512);

    // QK^T + mask + exp + pack, one jm (16-k slab) at a time: S transient
    short4v pk[4][4];                // [half][jm]
    #pragma unroll
    for (int jm = 0; jm < 4; jm++) {
      float4v sv[4] = {};
      __builtin_amdgcn_s_setprio(1);
      #pragma unroll
      for (int hh = 0; hh < 4; hh++)
        sv[hh] = __builtin_amdgcn_mfma_f32_16x16x32_bf16(kf[jm], qf[hh][0],
                                                         sv[hh], 0, 0, 0);
      #pragma unroll
      for (int hh = 0; hh < 4; hh++)
        sv[hh] = __builtin_amdgcn_mfma_f32_16x16x32_bf16(kf[4 + jm], qf[hh][1],
                                                         sv[hh], 0, 0, 0);
      __builtin_amdgcn_s_setprio(0);

      if (kt == qt) {                // diagonal tile: causal mask
        const int kv = kt * 64 + jm * 16 + quad * 4;
        #pragma unroll
        for (int hh = 0; hh < 4; hh++)
          #pragma unroll
          for (int r = 0; r < 4; r++)
            if (kv + r > qg[hh]) sv[hh][r] = -INFINITY;
      }

      #pragma unroll
      for (int hh = 0; hh < 4; hh++) {
        float p0 = __builtin_amdgcn_exp2f(sv[hh][0]);
        float p1 = __builtin_amdgcn_exp2f(sv[hh][1]);
        float p2 = __builtin_amdgcn_exp2f(sv[hh][2]);
        float p3 = __builtin_amdgcn_exp2f(sv[hh][3]);
        l[hh] += (p0 + p1) + (p2 + p3);
        pk[hh][jm] = cvt_pk_bf16x4(p0, p1, p2, p3);
      }
    }

    // O^T += V^T * P^T, V frag reused across the 4 halves
    __builtin_amdgcn_s_setprio(1);
    #pragma unroll
    for (int id = 0; id < 8; id++) {
      const int kwp = id >> 2, dm = id & 3;
      const short8v v8 = vv[id];
      const short4v v0 = {v8[0], v8[1], v8[2], v8[3]};
      const short4v v1 = {v8[4], v8[5], v8[6], v8[7]};
      #pragma unroll
      for (int hh = 0; hh < 4; hh++) {
        O[hh][dm] = __builtin_amdgcn_mfma_f32_16x16x16bf16_1k(v0, pk[hh][kwp * 2],
                                                              O[hh][dm], 0, 0, 0);
        O[hh][dm] = __builtin_amdgcn_mfma_f32_16x16x16bf16_1k(v1, pk[hh][kwp * 2 + 1],
                                                              O[hh][dm], 0, 0, 0);
      }
    }
    __builtin_amdgcn_s_setprio(0);
  }

  // epilogue: reduce l over the quad group; write UNNORMALIZED bf16 partial
  #pragma unroll
  for (int hh = 0; hh < 4; hh++) {
    l[hh] += __shfl_xor(l[hh], 16);
    l[hh] += __shfl_xor(l[hh], 32);
  }
  const int i = bh * 80 + s;
  short* pp = (i < 2048) ? (P0 + (size_t)i * 4096) : (P1 + (size_t)(i - 2048) * 4096);
  #pragma unroll
  for (int hh = 0; hh < 4; hh++) {
    const int row = hh * 16 + l16;
    if (quad == 0) lp[(size_t)i * 64 + row] = l[hh];
    short* pr = pp + row * 64;
    #pragma unroll
    for (int dm = 0; dm < 4; dm++)
      *(short4v*)(pr + dm * 16 + quad * 4) =
          pack_bf16x4(O[hh][dm][0], O[hh][dm][1], O[hh][dm][2], O[hh][dm][3]);
  }
}

// ---------------- merge split-K partials -> normalized bf16 aout ------------
__global__ __launch_bounds__(256) void merge_attn(
    const short* __restrict__ P0, const short* __restrict__ P1,
    const float* __restrict__ lp, short* __restrict__ aout)
{
  const int idx = blockIdx.x * 256 + threadIdx.x;   // 524288
  const int q = idx >> 7;
  const int rest = idx & 127;
  const int h  = rest >> 3;
  const int dg = (rest & 7) * 8;
  const int b  = q >> 11;
  const int qr = q & 2047;
  const int qt = qr >> 6;
  const int row = qr & 63;
  const int a = qt >> 3, bq = qt & 7;
  const int off = qt + 4 * a * (a - 1) + a * bq;
  const int nc  = a + 1;
  const int bh  = b * 16 + h;

  float acc[8] = {};
  float suml = 0.0f;
  for (int c = 0; c < nc; c++) {
    const int i = bh * 80 + off + c;
    const short* pp = (i < 2048) ? (P0 + (size_t)i * 4096) : (P1 + (size_t)(i - 2048) * 4096);
    const short8v o = *(const short8v*)(pp + row * 64 + dg);
    #pragma unroll
    for (int k = 0; k < 8; k++) acc[k] += bf2f(o[k]);
    suml += lp[(size_t)i * 64 + row];
  }
  const float inv = 1.0f / suml;
  short8v ov;
  #pragma unroll
  for (int k = 0; k < 8; k++) ov[k] = f2bf(acc[k] * inv);
  *(short8v*)(aout + (size_t)q * 1024 + h * 64 + dg) = ov;
}

extern "C" void kernel_launch(void* const* d_in, const int* in_sizes, int n_in,
                              void* d_out, int out_size, void* d_ws, size_t ws_size,
                              hipStream_t stream) {
  const float* hidden = (const float*)d_in[0];
  const float* w_attn = (const float*)d_in[1];
  const float* b_attn = (const float*)d_in[2];
  const float* w_proj = (const float*)d_in[3];
  const float* b_proj = (const float*)d_in[4];
  float* outp = (float*)d_out;

  char* ws = (char*)d_ws;
  short* hA     = (short*)(ws);                       // then attn P1 overflow
  float* lp     = (float*)(ws + 8ull  * 1024 * 1024); // 655 KB (ex-wqkvT space)
  short* wqkvT  = (short*)(ws + 8ull  * 1024 * 1024);
  short* wprojT = (short*)(ws + 14ull * 1024 * 1024);
  short* qkvb   = (short*)(ws + 16ull * 1024 * 1024);
  short* vAbuf  = (short*)(ws + 40ull * 1024 * 1024); // V frags, then aout
  short* aout   = (short*)(ws + 40ull * 1024 * 1024);
  short* P0     = (short*)d_out;                      // 16 MB partial region

  prep_kernel<<<8192, 256, 0, stream>>>(hidden, w_attn, w_proj, hA, wqkvT, wprojT);
  gemm_qkv256<<<dim3(12, 16), 512, 0, stream>>>(hA, wqkvT, b_attn, qkvb, vAbuf);
  attn_mfma<<<dim3(32, 80), 64, 0, stream>>>(qkvb, vAbuf, P0, hA, lp);
  merge_attn<<<2048, 256, 0, stream>>>(P0, hA, lp, aout);
  gemm_proj128<<<dim3(8, 32), 256, 0, stream>>>(aout, wprojT, b_proj, outp);
}